// Round 1
// baseline (2365.773 us; speedup 1.0000x reference)
//
#include <hip/hip_runtime.h>
#include <math.h>

#define N_NODES 20000
#define N_EDGES 256000
#define F_IN 1024
#define C_DIM 1000
#define C4 250          // C_DIM / 4 float4s per row
#define NEG_SLOPE 0.2f

// ===================== CSR build (by dst) =====================
__global__ void zero_counts_k(int* __restrict__ counts) {
  int i = blockIdx.x * blockDim.x + threadIdx.x;
  if (i < N_NODES) counts[i] = 0;
}

__global__ void count_k(const int* __restrict__ edst, int* __restrict__ counts) {
  int e = blockIdx.x * blockDim.x + threadIdx.x;
  if (e < N_EDGES) atomicAdd(&counts[edst[e]], 1);
}

__global__ __launch_bounds__(1024)
void scan_k(const int* __restrict__ counts, int* __restrict__ row_ptr, int* __restrict__ cursor) {
  __shared__ int sm[1024];
  __shared__ int carry_s;
  int tid = threadIdx.x;
  if (tid == 0) carry_s = 0;
  __syncthreads();
  for (int base = 0; base < N_NODES; base += 1024) {
    int idx = base + tid;
    int v = (idx < N_NODES) ? counts[idx] : 0;
    sm[tid] = v;
    __syncthreads();
    for (int off = 1; off < 1024; off <<= 1) {
      int t = (tid >= off) ? sm[tid - off] : 0;
      __syncthreads();
      sm[tid] += t;
      __syncthreads();
    }
    int incl = sm[tid];
    int c = carry_s;
    __syncthreads();
    if (tid == 1023) carry_s = c + incl;   // incl of tid 1023 == chunk total
    if (idx < N_NODES) { row_ptr[idx] = incl - v + c; cursor[idx] = incl - v + c; }
    __syncthreads();
  }
  if (tid == 0) row_ptr[N_NODES] = carry_s;
}

__global__ void scatter_k(const int* __restrict__ edst, int* __restrict__ cursor, int* __restrict__ eperm) {
  int e = blockIdx.x * blockDim.x + threadIdx.x;
  if (e < N_EDGES) {
    int p = atomicAdd(&cursor[edst[e]], 1);
    eperm[p] = e;
  }
}

// ===================== fp32 GEMM: C[M,N] = A[M,K] @ W[N,K]^T + bias =====================
#define BM 128
#define BN 128
#define BK 16

__global__ __launch_bounds__(256)
void gemm_nt_k(const float* __restrict__ A, const float* __restrict__ W,
               const float* __restrict__ bias, float* __restrict__ Cout,
               int M, int N, int K) {
  // LDS stride 132 keeps float4 16B alignment (132*4=528=33*16) and ~2-way banks
  __shared__ float As[BK][BM + 4];
  __shared__ float Bs[BK][BN + 4];
  int tid = threadIdx.x;
  int tx = tid & 15, ty = tid >> 4;
  int bm = blockIdx.y * BM;
  int bn = blockIdx.x * BN;

  float acc[8][8] = {};

  for (int k0 = 0; k0 < K; k0 += BK) {
    // ---- load A tile (BM x BK), store transposed As[k][m] ----
    #pragma unroll
    for (int r = 0; r < 2; ++r) {
      int f = tid + r * 256;        // float4 index 0..511
      int row = f >> 2;             // 0..127
      int kq = (f & 3) << 2;        // 0,4,8,12
      int gm = bm + row;
      int gk = k0 + kq;
      float4 v = make_float4(0.f, 0.f, 0.f, 0.f);
      if (gm < M && gk < K) {
        if (gk + 3 < K) {
          v = *(const float4*)(A + (long)gm * K + gk);
        } else {
          const float* p = A + (long)gm * K;
          v.x = p[gk];
          v.y = (gk + 1 < K) ? p[gk + 1] : 0.f;
          v.z = (gk + 2 < K) ? p[gk + 2] : 0.f;
          v.w = (gk + 3 < K) ? p[gk + 3] : 0.f;
        }
      }
      As[kq + 0][row] = v.x; As[kq + 1][row] = v.y;
      As[kq + 2][row] = v.z; As[kq + 3][row] = v.w;
    }
    // ---- load B tile (BN x BK) from W, store Bs[k][n] ----
    #pragma unroll
    for (int r = 0; r < 2; ++r) {
      int f = tid + r * 256;
      int row = f >> 2;
      int kq = (f & 3) << 2;
      int gn = bn + row;
      int gk = k0 + kq;
      float4 v = make_float4(0.f, 0.f, 0.f, 0.f);
      if (gn < N && gk < K) {
        if (gk + 3 < K) {
          v = *(const float4*)(W + (long)gn * K + gk);
        } else {
          const float* p = W + (long)gn * K;
          v.x = p[gk];
          v.y = (gk + 1 < K) ? p[gk + 1] : 0.f;
          v.z = (gk + 2 < K) ? p[gk + 2] : 0.f;
          v.w = (gk + 3 < K) ? p[gk + 3] : 0.f;
        }
      }
      Bs[kq + 0][row] = v.x; Bs[kq + 1][row] = v.y;
      Bs[kq + 2][row] = v.z; Bs[kq + 3][row] = v.w;
    }
    __syncthreads();

    #pragma unroll
    for (int k = 0; k < BK; ++k) {
      float a[8], b[8];
      *(float4*)&a[0] = *(const float4*)&As[k][ty * 4];
      *(float4*)&a[4] = *(const float4*)&As[k][64 + ty * 4];
      *(float4*)&b[0] = *(const float4*)&Bs[k][tx * 4];
      *(float4*)&b[4] = *(const float4*)&Bs[k][64 + tx * 4];
      #pragma unroll
      for (int i = 0; i < 8; ++i)
        #pragma unroll
        for (int j = 0; j < 8; ++j)
          acc[i][j] = fmaf(a[i], b[j], acc[i][j]);
    }
    __syncthreads();
  }

  // ---- epilogue: += bias, store ----
  #pragma unroll
  for (int i = 0; i < 8; ++i) {
    int gm = bm + ((i < 4) ? (ty * 4 + i) : (64 + ty * 4 + i - 4));
    if (gm >= M) continue;
    #pragma unroll
    for (int h = 0; h < 2; ++h) {
      int gn0 = bn + ((h == 0) ? (tx * 4) : (64 + tx * 4));
      if (gn0 + 3 < N) {
        float4 o;
        o.x = acc[i][h * 4 + 0] + bias[gn0 + 0];
        o.y = acc[i][h * 4 + 1] + bias[gn0 + 1];
        o.z = acc[i][h * 4 + 2] + bias[gn0 + 2];
        o.w = acc[i][h * 4 + 3] + bias[gn0 + 3];
        *(float4*)(Cout + (long)gm * N + gn0) = o;
      } else {
        #pragma unroll
        for (int j = 0; j < 4; ++j) {
          int gn = gn0 + j;
          if (gn < N) Cout[(long)gm * N + gn] = acc[i][h * 4 + j] + bias[gn];
        }
      }
    }
  }
}

// ===================== fused per-dst attention + aggregation =====================
// wave (64 lanes) per dst node; online softmax (flash-style), single pass over edges.
// ACT: 0 = relu (layer 1), 1 = sigmoid (layer 2)
template <int ACT>
__global__ __launch_bounds__(256)
void edge_agg_k(const float* __restrict__ xl, const float* __restrict__ xr,
                const float* __restrict__ eattr, const int* __restrict__ esrc,
                const int* __restrict__ row_ptr, const int* __restrict__ eperm,
                const float* __restrict__ We, const float* __restrict__ att,
                const float* __restrict__ bias, float* __restrict__ out) {
  int wave = threadIdx.x >> 6;
  int lane = threadIdx.x & 63;
  int d = blockIdx.x * 4 + wave;
  if (d >= N_NODES) return;
  int beg = row_ptr[d];
  int end = row_ptr[d + 1];

  // per-lane channel slice: float4 q = lane + 64*j, j=0..3 (q<250)
  float4 xr4[4], att4[4], We4[4];
  const float4* xrp = (const float4*)(xr + (long)d * C_DIM);
  #pragma unroll
  for (int j = 0; j < 4; ++j) {
    int q = lane + 64 * j;
    if (q < C4) {
      xr4[j] = xrp[q];
      att4[j] = ((const float4*)att)[q];
      We4[j] = ((const float4*)We)[q];
    } else {
      xr4[j] = make_float4(0.f, 0.f, 0.f, 0.f);
      att4[j] = make_float4(0.f, 0.f, 0.f, 0.f);
      We4[j] = make_float4(0.f, 0.f, 0.f, 0.f);
    }
  }

  float m = -INFINITY;
  float denom = 0.f;
  float4 acc[4];
  #pragma unroll
  for (int j = 0; j < 4; ++j) acc[j] = make_float4(0.f, 0.f, 0.f, 0.f);

  for (int i = beg; i < end; ++i) {
    int e = eperm[i];
    int s = esrc[e];
    float ea = eattr[e];
    const float4* xs = (const float4*)(xl + (long)s * C_DIM);
    float4 v[4];
    float part = 0.f;
    #pragma unroll
    for (int j = 0; j < 4; ++j) {
      int q = lane + 64 * j;
      if (q < C4) {
        v[j] = xs[q];
        float t;
        t = v[j].x + xr4[j].x + ea * We4[j].x; t = (t >= 0.f) ? t : NEG_SLOPE * t; part = fmaf(att4[j].x, t, part);
        t = v[j].y + xr4[j].y + ea * We4[j].y; t = (t >= 0.f) ? t : NEG_SLOPE * t; part = fmaf(att4[j].y, t, part);
        t = v[j].z + xr4[j].z + ea * We4[j].z; t = (t >= 0.f) ? t : NEG_SLOPE * t; part = fmaf(att4[j].z, t, part);
        t = v[j].w + xr4[j].w + ea * We4[j].w; t = (t >= 0.f) ? t : NEG_SLOPE * t; part = fmaf(att4[j].w, t, part);
      } else {
        v[j] = make_float4(0.f, 0.f, 0.f, 0.f);
      }
    }
    #pragma unroll
    for (int off = 32; off > 0; off >>= 1) part += __shfl_xor(part, off, 64);
    // online softmax update (wave-uniform branch)
    if (part > m) {
      float scale = __expf(m - part);   // first iter: exp(-inf)=0
      denom = denom * scale + 1.f;      // new element has weight exp(0)=1
      #pragma unroll
      for (int j = 0; j < 4; ++j) {
        acc[j].x = fmaf(acc[j].x, scale, v[j].x);
        acc[j].y = fmaf(acc[j].y, scale, v[j].y);
        acc[j].z = fmaf(acc[j].z, scale, v[j].z);
        acc[j].w = fmaf(acc[j].w, scale, v[j].w);
      }
      m = part;
    } else {
      float w = __expf(part - m);
      denom += w;
      #pragma unroll
      for (int j = 0; j < 4; ++j) {
        acc[j].x = fmaf(w, v[j].x, acc[j].x);
        acc[j].y = fmaf(w, v[j].y, acc[j].y);
        acc[j].z = fmaf(w, v[j].z, acc[j].z);
        acc[j].w = fmaf(w, v[j].w, acc[j].w);
      }
    }
  }

  float inv = 1.f / (denom + 1e-16f);
  float4* op = (float4*)(out + (long)d * C_DIM);
  const float4* bp = (const float4*)bias;
  #pragma unroll
  for (int j = 0; j < 4; ++j) {
    int q = lane + 64 * j;
    if (q < C4) {
      float4 b = bp[q];
      float4 o;
      o.x = fmaf(acc[j].x, inv, b.x);
      o.y = fmaf(acc[j].y, inv, b.y);
      o.z = fmaf(acc[j].z, inv, b.z);
      o.w = fmaf(acc[j].w, inv, b.w);
      if (ACT == 0) {
        o.x = fmaxf(o.x, 0.f); o.y = fmaxf(o.y, 0.f);
        o.z = fmaxf(o.z, 0.f); o.w = fmaxf(o.w, 0.f);
      } else {
        o.x = 1.f / (1.f + __expf(-o.x));
        o.y = 1.f / (1.f + __expf(-o.y));
        o.z = 1.f / (1.f + __expf(-o.z));
        o.w = 1.f / (1.f + __expf(-o.w));
      }
      op[q] = o;
    }
  }
}

// ===================== launch =====================
extern "C" void kernel_launch(void* const* d_in, const int* in_sizes, int n_in,
                              void* d_out, int out_size, void* d_ws, size_t ws_size,
                              hipStream_t stream) {
  const float* x     = (const float*)d_in[0];
  const int*   ei    = (const int*)d_in[1];     // [2, E] int32
  const float* eattr = (const float*)d_in[2];   // [E, 1]
  const float* w1l   = (const float*)d_in[3];
  const float* b1l   = (const float*)d_in[4];
  const float* w1r   = (const float*)d_in[5];
  const float* b1r   = (const float*)d_in[6];
  const float* w1e   = (const float*)d_in[7];
  const float* att1  = (const float*)d_in[8];
  const float* bias1 = (const float*)d_in[9];
  const float* w2l   = (const float*)d_in[10];
  const float* b2l   = (const float*)d_in[11];
  const float* w2r   = (const float*)d_in[12];
  const float* b2r   = (const float*)d_in[13];
  const float* w2e   = (const float*)d_in[14];
  const float* att2  = (const float*)d_in[15];
  const float* bias2 = (const float*)d_in[16];
  float* out = (float*)d_out;

  // workspace layout: xl (20M f32) | xr (20M f32) | row_ptr | cursor | counts | eperm
  float* xl = (float*)d_ws;
  float* xr = xl + (long)N_NODES * C_DIM;
  int* row_ptr = (int*)(xr + (long)N_NODES * C_DIM);
  int* cursor  = row_ptr + (N_NODES + 1);
  int* counts  = cursor + N_NODES;
  int* eperm   = counts + N_NODES;

  const int* esrc = ei;
  const int* edst = ei + N_EDGES;

  // ---- CSR by dst (deterministic counts/offsets; within-segment order may vary,
  //      only perturbs fp summation order ~1e-7) ----
  zero_counts_k<<<(N_NODES + 255) / 256, 256, 0, stream>>>(counts);
  count_k<<<(N_EDGES + 255) / 256, 256, 0, stream>>>(edst, counts);
  scan_k<<<1, 1024, 0, stream>>>(counts, row_ptr, cursor);
  scatter_k<<<(N_EDGES + 255) / 256, 256, 0, stream>>>(edst, cursor, eperm);

  dim3 ggrid((C_DIM + BN - 1) / BN, (N_NODES + BM - 1) / BM);

  // ---- layer 1 ----
  gemm_nt_k<<<ggrid, 256, 0, stream>>>(x, w1l, b1l, xl, N_NODES, C_DIM, F_IN);
  gemm_nt_k<<<ggrid, 256, 0, stream>>>(x, w1r, b1r, xr, N_NODES, C_DIM, F_IN);
  edge_agg_k<0><<<(N_NODES + 3) / 4, 256, 0, stream>>>(xl, xr, eattr, esrc, row_ptr, eperm,
                                                       w1e, att1, bias1, out);  // h -> d_out

  // ---- layer 2 (h read from d_out; final pass overwrites d_out) ----
  gemm_nt_k<<<ggrid, 256, 0, stream>>>(out, w2l, b2l, xl, N_NODES, C_DIM, C_DIM);
  gemm_nt_k<<<ggrid, 256, 0, stream>>>(out, w2r, b2r, xr, N_NODES, C_DIM, C_DIM);
  edge_agg_k<1><<<(N_NODES + 3) / 4, 256, 0, stream>>>(xl, xr, eattr, esrc, row_ptr, eperm,
                                                       w2e, att2, bias2, out);
}

// Round 2
// 745.120 us; speedup vs baseline: 3.1750x; 3.1750x over previous
//
#include <hip/hip_runtime.h>
#include <math.h>

#define N_NODES 20000
#define N_EDGES 256000
#define F_IN 1024
#define C_DIM 1000
#define NEG_SLOPE 0.2f

#define MPAD 20096   // 157 * 128
#define KDIM 1024    // padded K for both layers
#define NPAD 1024    // padded N (output cols) for weights

typedef __attribute__((ext_vector_type(8))) short     bf16x8;
typedef __attribute__((ext_vector_type(8))) unsigned short u16x8;
typedef __attribute__((ext_vector_type(4))) float     f32x4;

__device__ __forceinline__ unsigned short f2bf(float f) {
  unsigned u = __float_as_uint(f);
  unsigned r = (u + 0x7FFFu + ((u >> 16) & 1u)) >> 16;   // RNE
  return (unsigned short)r;
}
__device__ __forceinline__ float bf2f(unsigned short u) {
  return __uint_as_float(((unsigned)u) << 16);
}

__device__ __forceinline__ void gld16(void* lds, const void* g) {
  // async global->LDS, 16B per lane; LDS dest = wave-uniform base + lane*16
  __builtin_amdgcn_global_load_lds(
      (const __attribute__((address_space(1))) unsigned int*)g,
      (__attribute__((address_space(3))) unsigned int*)lds, 16, 0, 0);
}

// ===================== CSR build (by dst) =====================
__global__ void zero_counts_k(int* __restrict__ counts) {
  int i = blockIdx.x * blockDim.x + threadIdx.x;
  if (i < N_NODES) counts[i] = 0;
}

__global__ void count_k(const int* __restrict__ edst, int* __restrict__ counts) {
  int e = blockIdx.x * blockDim.x + threadIdx.x;
  if (e < N_EDGES) atomicAdd(&counts[edst[e]], 1);
}

__global__ __launch_bounds__(1024)
void scan_k(const int* __restrict__ counts, int* __restrict__ row_ptr, int* __restrict__ cursor) {
  __shared__ int sm[1024];
  __shared__ int carry_s;
  int tid = threadIdx.x;
  if (tid == 0) carry_s = 0;
  __syncthreads();
  for (int base = 0; base < N_NODES; base += 1024) {
    int idx = base + tid;
    int v = (idx < N_NODES) ? counts[idx] : 0;
    sm[tid] = v;
    __syncthreads();
    for (int off = 1; off < 1024; off <<= 1) {
      int t = (tid >= off) ? sm[tid - off] : 0;
      __syncthreads();
      sm[tid] += t;
      __syncthreads();
    }
    int incl = sm[tid];
    int c = carry_s;
    __syncthreads();
    if (tid == 1023) carry_s = c + incl;
    if (idx < N_NODES) { row_ptr[idx] = incl - v + c; cursor[idx] = incl - v + c; }
    __syncthreads();
  }
  if (tid == 0) row_ptr[N_NODES] = carry_s;
}

__global__ void scatter_k(const int* __restrict__ edst, int* __restrict__ cursor, int* __restrict__ eperm) {
  int e = blockIdx.x * blockDim.x + threadIdx.x;
  if (e < N_EDGES) {
    int p = atomicAdd(&cursor[edst[e]], 1);
    eperm[p] = e;
  }
}

// ===================== fp32 -> padded bf16 (rows padded to dstRows, cols to 1024) =====
__global__ void cvt_pad_k(const float* __restrict__ src, unsigned short* __restrict__ dst,
                          int R, int C, int dstRows) {
  long total = (long)dstRows * 256;   // one ushort4 (4 cols) per index
  for (long i = (long)blockIdx.x * blockDim.x + threadIdx.x; i < total;
       i += (long)gridDim.x * blockDim.x) {
    int row = (int)(i >> 8);
    int c = ((int)(i & 255)) << 2;
    ushort4 o = make_ushort4(0, 0, 0, 0);
    if (row < R && c < C) {
      float4 v = *(const float4*)(src + (long)row * C + c);
      o.x = f2bf(v.x); o.y = f2bf(v.y); o.z = f2bf(v.z); o.w = f2bf(v.w);
    }
    *(ushort4*)(dst + ((long)row << 10) + c) = o;
  }
}

// ===================== bf16 MFMA GEMM (m97 structure) =====================
// C_bf[M=20000][1000] = A_bf[MPAD][1024] @ W_bf[NPAD][1024]^T + bias(fp32), output bf16.
// 128x128 tile, BK=32, 256 threads = 4 waves (2x2), wave tile 64x64 (4x4 frags 16x16).
__global__ __launch_bounds__(256)
void gemm_mfma_k(const unsigned short* __restrict__ Abf,
                 const unsigned short* __restrict__ Wbf,
                 const float* __restrict__ bias,
                 unsigned short* __restrict__ Cbf) {
  __shared__ unsigned short As[128 * 32];
  __shared__ unsigned short Bs[128 * 32];
  const int tid = threadIdx.x;
  const int lane = tid & 63;
  const int wv = tid >> 6;
  const int wr = wv >> 1, wc = wv & 1;
  const long bm = (long)blockIdx.y * 128;
  const long bn = (long)blockIdx.x * 128;

  f32x4 acc[4][4];
  const f32x4 z4 = {0.f, 0.f, 0.f, 0.f};
#pragma unroll
  for (int i = 0; i < 4; ++i)
#pragma unroll
    for (int j = 0; j < 4; ++j) acc[i][j] = z4;

  // staging: 512 16B-chunks per tile; idx -> row=idx>>2, kchunk=(idx&3)*8
  const int i0 = tid, i1 = tid + 256;
  const unsigned short* gA0 = Abf + (bm + (i0 >> 2)) * KDIM + (i0 & 3) * 8;
  const unsigned short* gA1 = Abf + (bm + (i1 >> 2)) * KDIM + (i1 & 3) * 8;
  const unsigned short* gB0 = Wbf + (bn + (i0 >> 2)) * KDIM + (i0 & 3) * 8;
  const unsigned short* gB1 = Wbf + (bn + (i1 >> 2)) * KDIM + (i1 & 3) * 8;
  unsigned short* lA0 = As + wv * 512;          // bytes: wv*1024
  unsigned short* lA1 = As + 2048 + wv * 512;   // + issue-1 offset 4096B
  unsigned short* lB0 = Bs + wv * 512;
  unsigned short* lB1 = Bs + 2048 + wv * 512;

  const int g = lane >> 4;       // k-group 0..3
  const int rA = lane & 15;      // row within fragment

  for (int k0 = 0; k0 < KDIM; k0 += 32) {
    gld16(lA0, gA0 + k0);
    gld16(lA1, gA1 + k0);
    gld16(lB0, gB0 + k0);
    gld16(lB1, gB1 + k0);
    __syncthreads();   // vmcnt(0) drain + barrier: staged tile visible

    bf16x8 av[4], bv[4];
#pragma unroll
    for (int mi = 0; mi < 4; ++mi)
      av[mi] = *(const bf16x8*)&As[(wr * 64 + mi * 16 + rA) * 32 + g * 8];
#pragma unroll
    for (int ni = 0; ni < 4; ++ni)
      bv[ni] = *(const bf16x8*)&Bs[(wc * 64 + ni * 16 + rA) * 32 + g * 8];

#pragma unroll
    for (int mi = 0; mi < 4; ++mi)
#pragma unroll
      for (int ni = 0; ni < 4; ++ni)
        acc[mi][ni] = __builtin_amdgcn_mfma_f32_16x16x32_bf16(av[mi], bv[ni], acc[mi][ni], 0, 0, 0);

    __syncthreads();   // protect LDS from next iteration's staging
  }

  // epilogue: + bias, cast bf16, bounds-checked store
  float biasv[4];
  int coln[4];
#pragma unroll
  for (int ni = 0; ni < 4; ++ni) {
    coln[ni] = (int)bn + wc * 64 + ni * 16 + (lane & 15);
    biasv[ni] = (coln[ni] < C_DIM) ? bias[coln[ni]] : 0.f;
  }
#pragma unroll
  for (int mi = 0; mi < 4; ++mi) {
#pragma unroll
    for (int j = 0; j < 4; ++j) {
      int row = (int)bm + wr * 64 + mi * 16 + (lane >> 4) * 4 + j;
      if (row < N_NODES) {
#pragma unroll
        for (int ni = 0; ni < 4; ++ni) {
          if (coln[ni] < C_DIM)
            Cbf[(long)row * C_DIM + coln[ni]] = f2bf(acc[mi][ni][j] + biasv[ni]);
        }
      }
    }
  }
}

// ===================== fused per-dst attention + aggregation (bf16 xl/xr) ==========
// wave per dst; online softmax; xl/xr are bf16 [N_NODES][C_DIM].
// ACT: 0 = relu (layer 1 -> fp32 h), 1 = sigmoid (layer 2 -> fp32 out)
template <int ACT>
__global__ __launch_bounds__(256)
void edge_agg_k(const unsigned short* __restrict__ xl, const unsigned short* __restrict__ xr,
                const float* __restrict__ eattr, const int* __restrict__ esrc,
                const int* __restrict__ row_ptr, const int* __restrict__ eperm,
                const float* __restrict__ We, const float* __restrict__ att,
                const float* __restrict__ bias, float* __restrict__ out) {
  int wave = threadIdx.x >> 6;
  int lane = threadIdx.x & 63;
  int d = blockIdx.x * 4 + wave;
  if (d >= N_NODES) return;
  int beg = row_ptr[d];
  int end = row_ptr[d + 1];

  // per-lane channel slice: 16B chunk q = lane + 64*j (q < 125), 8 channels each
  float xrv[2][8], attv[2][8], wev[2][8];
#pragma unroll
  for (int j = 0; j < 2; ++j) {
    int q = lane + 64 * j;
    if (q < 125) {
      u16x8 h = ((const u16x8*)(xr + (long)d * C_DIM))[q];
      float4 a0 = ((const float4*)att)[2 * q], a1 = ((const float4*)att)[2 * q + 1];
      float4 w0 = ((const float4*)We)[2 * q], w1 = ((const float4*)We)[2 * q + 1];
      attv[j][0] = a0.x; attv[j][1] = a0.y; attv[j][2] = a0.z; attv[j][3] = a0.w;
      attv[j][4] = a1.x; attv[j][5] = a1.y; attv[j][6] = a1.z; attv[j][7] = a1.w;
      wev[j][0] = w0.x; wev[j][1] = w0.y; wev[j][2] = w0.z; wev[j][3] = w0.w;
      wev[j][4] = w1.x; wev[j][5] = w1.y; wev[j][6] = w1.z; wev[j][7] = w1.w;
#pragma unroll
      for (int t = 0; t < 8; ++t) xrv[j][t] = bf2f(h[t]);
    } else {
#pragma unroll
      for (int t = 0; t < 8; ++t) { xrv[j][t] = 0.f; attv[j][t] = 0.f; wev[j][t] = 0.f; }
    }
  }

  float m = -INFINITY;
  float denom = 0.f;
  float acc[2][8];
#pragma unroll
  for (int j = 0; j < 2; ++j)
#pragma unroll
    for (int t = 0; t < 8; ++t) acc[j][t] = 0.f;

  for (int i = beg; i < end; ++i) {
    int e = eperm[i];
    int s = esrc[e];
    float ea = eattr[e];
    const u16x8* xs = (const u16x8*)(xl + (long)s * C_DIM);
    float v[2][8];
    float part = 0.f;
#pragma unroll
    for (int j = 0; j < 2; ++j) {
      int q = lane + 64 * j;
      if (q < 125) {
        u16x8 h = xs[q];
#pragma unroll
        for (int t = 0; t < 8; ++t) {
          float vv = bf2f(h[t]);
          v[j][t] = vv;
          float tt = vv + xrv[j][t] + ea * wev[j][t];
          tt = (tt >= 0.f) ? tt : NEG_SLOPE * tt;
          part = fmaf(attv[j][t], tt, part);
        }
      } else {
#pragma unroll
        for (int t = 0; t < 8; ++t) v[j][t] = 0.f;
      }
    }
#pragma unroll
    for (int off = 32; off > 0; off >>= 1) part += __shfl_xor(part, off, 64);
    // online softmax update (wave-uniform branch)
    if (part > m) {
      float scale = __expf(m - part);   // first iter: exp(-inf)=0
      denom = denom * scale + 1.f;
#pragma unroll
      for (int j = 0; j < 2; ++j)
#pragma unroll
        for (int t = 0; t < 8; ++t) acc[j][t] = fmaf(acc[j][t], scale, v[j][t]);
      m = part;
    } else {
      float w = __expf(part - m);
      denom += w;
#pragma unroll
      for (int j = 0; j < 2; ++j)
#pragma unroll
        for (int t = 0; t < 8; ++t) acc[j][t] = fmaf(w, v[j][t], acc[j][t]);
    }
  }

  float inv = 1.f / (denom + 1e-16f);
#pragma unroll
  for (int j = 0; j < 2; ++j) {
    int q = lane + 64 * j;
    if (q < 125) {
      float o[8];
      const float4 b0 = ((const float4*)bias)[2 * q], b1 = ((const float4*)bias)[2 * q + 1];
      const float bb[8] = {b0.x, b0.y, b0.z, b0.w, b1.x, b1.y, b1.z, b1.w};
#pragma unroll
      for (int t = 0; t < 8; ++t) {
        float x = fmaf(acc[j][t], inv, bb[t]);
        if (ACT == 0) x = fmaxf(x, 0.f);
        else          x = 1.f / (1.f + __expf(-x));
        o[t] = x;
      }
      float4* op = (float4*)(out + (long)d * C_DIM + 8 * q);
      op[0] = make_float4(o[0], o[1], o[2], o[3]);
      op[1] = make_float4(o[4], o[5], o[6], o[7]);
    }
  }
}

// ===================== launch =====================
extern "C" void kernel_launch(void* const* d_in, const int* in_sizes, int n_in,
                              void* d_out, int out_size, void* d_ws, size_t ws_size,
                              hipStream_t stream) {
  const float* x     = (const float*)d_in[0];
  const int*   ei    = (const int*)d_in[1];
  const float* eattr = (const float*)d_in[2];
  const float* w1l   = (const float*)d_in[3];
  const float* b1l   = (const float*)d_in[4];
  const float* w1r   = (const float*)d_in[5];
  const float* b1r   = (const float*)d_in[6];
  const float* w1e   = (const float*)d_in[7];
  const float* att1  = (const float*)d_in[8];
  const float* bias1 = (const float*)d_in[9];
  const float* w2l   = (const float*)d_in[10];
  const float* b2l   = (const float*)d_in[11];
  const float* w2r   = (const float*)d_in[12];
  const float* b2r   = (const float*)d_in[13];
  const float* w2e   = (const float*)d_in[14];
  const float* att2  = (const float*)d_in[15];
  const float* bias2 = (const float*)d_in[16];
  float* out = (float*)d_out;

  // ws layout (bytes), total ~126.6 MB:
  //   xl_bf 40,000,000 | xr_bf 40,000,000 | Abf 41,156,608 | Wbf0 2,097,152 |
  //   Wbf1 2,097,152 | CSR ints
  char* w = (char*)d_ws;
  unsigned short* xl_bf = (unsigned short*)w;
  unsigned short* xr_bf = (unsigned short*)(w + 40000000L);
  unsigned short* Abf   = (unsigned short*)(w + 80000000L);
  unsigned short* Wbf0  = (unsigned short*)(w + 121156608L);
  unsigned short* Wbf1  = (unsigned short*)(w + 123253760L);
  int* row_ptr = (int*)(w + 125350912L);
  int* cursor  = row_ptr + (N_NODES + 1);
  int* counts  = cursor + N_NODES;
  int* eperm   = counts + N_NODES;

  const int* esrc = ei;
  const int* edst = ei + N_EDGES;

  // ---- CSR by dst ----
  zero_counts_k<<<(N_NODES + 255) / 256, 256, 0, stream>>>(counts);
  count_k<<<(N_EDGES + 255) / 256, 256, 0, stream>>>(edst, counts);
  scan_k<<<1, 1024, 0, stream>>>(counts, row_ptr, cursor);
  scatter_k<<<(N_EDGES + 255) / 256, 256, 0, stream>>>(edst, cursor, eperm);

  dim3 ggrid(NPAD / 128, MPAD / 128);   // (8, 157)

  // ---- layer 1 ----
  cvt_pad_k<<<4096, 256, 0, stream>>>(x, Abf, N_NODES, F_IN, MPAD);
  cvt_pad_k<<<1024, 256, 0, stream>>>(w1l, Wbf0, C_DIM, F_IN, NPAD);
  cvt_pad_k<<<1024, 256, 0, stream>>>(w1r, Wbf1, C_DIM, F_IN, NPAD);
  gemm_mfma_k<<<ggrid, 256, 0, stream>>>(Abf, Wbf0, b1l, xl_bf);
  gemm_mfma_k<<<ggrid, 256, 0, stream>>>(Abf, Wbf1, b1r, xr_bf);
  edge_agg_k<0><<<(N_NODES + 3) / 4, 256, 0, stream>>>(xl_bf, xr_bf, eattr, esrc, row_ptr,
                                                       eperm, w1e, att1, bias1, out);

  // ---- layer 2 (h in d_out fp32) ----
  cvt_pad_k<<<4096, 256, 0, stream>>>(out, Abf, N_NODES, C_DIM, MPAD);
  cvt_pad_k<<<1024, 256, 0, stream>>>(w2l, Wbf0, C_DIM, C_DIM, NPAD);
  cvt_pad_k<<<1024, 256, 0, stream>>>(w2r, Wbf1, C_DIM, C_DIM, NPAD);
  gemm_mfma_k<<<ggrid, 256, 0, stream>>>(Abf, Wbf0, b2l, xl_bf);
  gemm_mfma_k<<<ggrid, 256, 0, stream>>>(Abf, Wbf1, b2r, xr_bf);
  edge_agg_k<1><<<(N_NODES + 3) / 4, 256, 0, stream>>>(xl_bf, xr_bf, eattr, esrc, row_ptr,
                                                       eperm, w2e, att2, bias2, out);
}

// Round 3
// 521.521 us; speedup vs baseline: 4.5363x; 1.4287x over previous
//
#include <hip/hip_runtime.h>
#include <math.h>

#define N_NODES 20000
#define N_EDGES 256000
#define F_IN 1024
#define C_DIM 1000
#define NEG_SLOPE 0.2f

#define MPAD 20096   // 157 * 128
#define KDIM 1024    // padded K for both layers
#define NW 2048      // fused weight rows: [0,1000)=Wl, [1024,2024)=Wr

typedef __attribute__((ext_vector_type(8))) short          bf16x8;
typedef __attribute__((ext_vector_type(8))) unsigned short u16x8;
typedef __attribute__((ext_vector_type(4))) float          f32x4;
typedef unsigned short us;

__device__ __forceinline__ us f2bf(float f) {
  unsigned u = __float_as_uint(f);
  return (us)((u + 0x7FFFu + ((u >> 16) & 1u)) >> 16);   // RNE
}
__device__ __forceinline__ float bf2f(us u) {
  return __uint_as_float(((unsigned)u) << 16);
}

__device__ __forceinline__ void gld16(void* lds, const void* g) {
  __builtin_amdgcn_global_load_lds(
      (const __attribute__((address_space(1))) unsigned int*)g,
      (__attribute__((address_space(3))) unsigned int*)lds, 16, 0, 0);
}

// ===================== CSR build (by dst) =====================
__global__ void count_k(const int* __restrict__ edst, int* __restrict__ counts) {
  int e = blockIdx.x * blockDim.x + threadIdx.x;
  if (e < N_EDGES) atomicAdd(&counts[edst[e]], 1);
}

// one block; thread t owns counts[t*20 .. t*20+19]
__global__ __launch_bounds__(1024)
void scan_k(const int* __restrict__ counts, int* __restrict__ row_ptr, int* __restrict__ cursor) {
  __shared__ int sm[1024];
  int t = threadIdx.x;
  int base = t * 20;
  int loc[20];
  int run = 0;
#pragma unroll
  for (int i = 0; i < 20; ++i) {
    int idx = base + i;
    int v = (idx < N_NODES) ? counts[idx] : 0;
    run += v;
    loc[i] = run;                      // inclusive within thread
  }
  sm[t] = run;
  __syncthreads();
  for (int off = 1; off < 1024; off <<= 1) {
    int v = (t >= off) ? sm[t - off] : 0;
    __syncthreads();
    sm[t] += v;
    __syncthreads();
  }
  int excl = (t > 0) ? sm[t - 1] : 0;
#pragma unroll
  for (int i = 0; i < 20; ++i) {
    int idx = base + i;
    if (idx < N_NODES) {
      int e = excl + ((i > 0) ? loc[i - 1] : 0);
      row_ptr[idx] = e;
      cursor[idx] = e;
    }
  }
  if (t == 0) row_ptr[N_NODES] = sm[1023];
}

// build dst-sorted (src, eattr) pairs: kills the eperm indirection in the hot loop
__global__ void scatter_k(const int* __restrict__ esrc, const float* __restrict__ eattr,
                          const int* __restrict__ edst, int* __restrict__ cursor,
                          int2* __restrict__ spair) {
  int e = blockIdx.x * blockDim.x + threadIdx.x;
  if (e < N_EDGES) {
    int p = atomicAdd(&cursor[edst[e]], 1);
    spair[p] = make_int2(esrc[e], __float_as_int(eattr[e]));
  }
}

// ===================== fp32 -> padded bf16 (rows -> dstRows, cols -> 1024) =====
__global__ void cvt_pad_k(const float* __restrict__ src, us* __restrict__ dst,
                          int R, int C, int dstRows) {
  long total = (long)dstRows * 256;   // one ushort4 (4 cols) per index
  for (long i = (long)blockIdx.x * blockDim.x + threadIdx.x; i < total;
       i += (long)gridDim.x * blockDim.x) {
    int row = (int)(i >> 8);
    int c = ((int)(i & 255)) << 2;
    ushort4 o = make_ushort4(0, 0, 0, 0);
    if (row < R && c < C) {
      float4 v = *(const float4*)(src + (long)row * C + c);
      o.x = f2bf(v.x); o.y = f2bf(v.y); o.z = f2bf(v.z); o.w = f2bf(v.w);
    }
    *(ushort4*)(dst + ((long)row << 10) + c) = o;
  }
}

// ===================== fused bf16 MFMA GEMM: C[M,2048] = A[MPAD,1024] @ W2[2048,1024]^T =====
// 128x128 tile, BK=32, 2-phase double-buffered staging, XCD-chunked block swizzle.
__global__ __launch_bounds__(256)
void gemm_mfma_k(const us* __restrict__ Abf, const us* __restrict__ Wbf,
                 const float* __restrict__ bl, const float* __restrict__ br,
                 us* __restrict__ Cbf) {
  __shared__ us As0[4096], As1[4096], Bs0[4096], Bs1[4096];
  const int tid = threadIdx.x;
  const int lane = tid & 63;
  const int wv = tid >> 6;
  const int wr = wv >> 1, wc = wv & 1;

  // bijective XCD swizzle: nwg = 2512 (%8==0). Each XCD gets a contiguous wg
  // chunk -> its A-slice (~5MB) has L2 locality instead of streaming all 41MB.
  const int nwg = gridDim.x;
  const int q = nwg >> 3;
  const int wg = (blockIdx.x & 7) * q + (blockIdx.x >> 3);
  const long bm = (long)(wg >> 4) * 128;   // 157 row-tiles
  const long bn = (long)(wg & 15) * 128;   // 16 col-tiles (N=2048)

  f32x4 acc[4][4];
  const f32x4 z4 = {0.f, 0.f, 0.f, 0.f};
#pragma unroll
  for (int i = 0; i < 4; ++i)
#pragma unroll
    for (int j = 0; j < 4; ++j) acc[i][j] = z4;

  // staging: 512 16B chunks/tile; chunk c -> row c>>2, kchunk (c&3)*8; LDS off = 16c B
  const int i0 = tid, i1 = tid + 256;
  const us* gA0 = Abf + (bm + (i0 >> 2)) * KDIM + (i0 & 3) * 8;
  const us* gA1 = Abf + (bm + (i1 >> 2)) * KDIM + (i1 & 3) * 8;
  const us* gB0 = Wbf + (bn + (i0 >> 2)) * KDIM + (i0 & 3) * 8;
  const us* gB1 = Wbf + (bn + (i1 >> 2)) * KDIM + (i1 & 3) * 8;

  const int g = lane >> 4;       // k-group 0..3
  const int rA = lane & 15;

  // prologue: stage tile 0 into buf0
  gld16(As0 + wv * 512, gA0);
  gld16(As0 + 2048 + wv * 512, gA1);
  gld16(Bs0 + wv * 512, gB0);
  gld16(Bs0 + 2048 + wv * 512, gB1);
  __syncthreads();

  for (int t = 0; t < 32; ++t) {
    if (t + 1 < 32) {                          // stage next tile into other buffer
      int kn = (t + 1) << 5;
      us* dA = ((t + 1) & 1) ? As1 : As0;
      us* dB = ((t + 1) & 1) ? Bs1 : Bs0;
      gld16(dA + wv * 512, gA0 + kn);
      gld16(dA + 2048 + wv * 512, gA1 + kn);
      gld16(dB + wv * 512, gB0 + kn);
      gld16(dB + 2048 + wv * 512, gB1 + kn);
    }
    const us* Ar = (t & 1) ? As1 : As0;
    const us* Br = (t & 1) ? Bs1 : Bs0;
    bf16x8 av[4], bv[4];
#pragma unroll
    for (int mi = 0; mi < 4; ++mi)
      av[mi] = *(const bf16x8*)&Ar[(wr * 64 + mi * 16 + rA) * 32 + g * 8];
#pragma unroll
    for (int ni = 0; ni < 4; ++ni)
      bv[ni] = *(const bf16x8*)&Br[(wc * 64 + ni * 16 + rA) * 32 + g * 8];
#pragma unroll
    for (int mi = 0; mi < 4; ++mi)
#pragma unroll
      for (int ni = 0; ni < 4; ++ni)
        acc[mi][ni] = __builtin_amdgcn_mfma_f32_16x16x32_bf16(av[mi], bv[ni], acc[mi][ni], 0, 0, 0);
    __syncthreads();   // drains this iter's stage (vmcnt0) + protects read buffer
  }

  // epilogue
  int coln[4]; float biasv[4]; int cok[4];
#pragma unroll
  for (int ni = 0; ni < 4; ++ni) {
    coln[ni] = (int)bn + wc * 64 + ni * 16 + rA;
    int cm = coln[ni] & 1023;
    cok[ni] = (cm < C_DIM);
    biasv[ni] = cok[ni] ? ((coln[ni] < 1024) ? bl[cm] : br[cm]) : 0.f;
  }
#pragma unroll
  for (int mi = 0; mi < 4; ++mi) {
#pragma unroll
    for (int j = 0; j < 4; ++j) {
      int row = (int)bm + wr * 64 + mi * 16 + g * 4 + j;
      if (row < N_NODES) {
#pragma unroll
        for (int ni = 0; ni < 4; ++ni)
          if (cok[ni])
            Cbf[(long)row * NW + coln[ni]] = f2bf(acc[mi][ni][j] + biasv[ni]);
      }
    }
  }
}

// ===================== fused per-dst attention + aggregation =====================
// wave per dst (grid-stride persistent); online softmax; edges unrolled x2.
// xlr: [N_NODES][2048] bf16, xl = cols 0..999, xr = cols 1024..2023.
// ACT 0: relu -> bf16 into hout [MPAD][1024] (pad cols zeroed). ACT 1: sigmoid -> fp32 fout.
template <int ACT>
__global__ __launch_bounds__(256)
void edge_agg_k(const us* __restrict__ xlr, const int2* __restrict__ spair,
                const int* __restrict__ row_ptr,
                const float* __restrict__ We, const float* __restrict__ att,
                const float* __restrict__ bias, us* __restrict__ hout,
                float* __restrict__ fout) {
  const int wave = threadIdx.x >> 6;
  const int lane = threadIdx.x & 63;
  const int q0 = lane, q1 = lane + 64;         // 16B chunk ids (valid < 125)
  const bool ok1 = (q1 < 125);

  // dst-invariant per-lane params
  float attv[2][8], wev[2][8];
#pragma unroll
  for (int j = 0; j < 2; ++j) {
    int qq = lane + 64 * j;
    if (qq < 125) {
      float4 a0 = ((const float4*)att)[2 * qq], a1 = ((const float4*)att)[2 * qq + 1];
      float4 w0 = ((const float4*)We)[2 * qq],  w1 = ((const float4*)We)[2 * qq + 1];
      attv[j][0] = a0.x; attv[j][1] = a0.y; attv[j][2] = a0.z; attv[j][3] = a0.w;
      attv[j][4] = a1.x; attv[j][5] = a1.y; attv[j][6] = a1.z; attv[j][7] = a1.w;
      wev[j][0] = w0.x; wev[j][1] = w0.y; wev[j][2] = w0.z; wev[j][3] = w0.w;
      wev[j][4] = w1.x; wev[j][5] = w1.y; wev[j][6] = w1.z; wev[j][7] = w1.w;
    } else {
#pragma unroll
      for (int t = 0; t < 8; ++t) { attv[j][t] = 0.f; wev[j][t] = 0.f; }
    }
  }

  const int gw = (blockIdx.x << 2) | wave;
  const int stride = gridDim.x << 2;

  for (int d = gw; d < N_NODES; d += stride) {
    const int beg = row_ptr[d];
    const int end = row_ptr[d + 1];

    float xrv[2][8];
    {
      const u16x8* xrp = (const u16x8*)(xlr + (long)d * NW + 1024);
#pragma unroll
      for (int j = 0; j < 2; ++j) {
        int qq = lane + 64 * j;
        if (qq < 125) {
          u16x8 h = xrp[qq];
#pragma unroll
          for (int t = 0; t < 8; ++t) xrv[j][t] = bf2f(h[t]);
        } else {
#pragma unroll
          for (int t = 0; t < 8; ++t) xrv[j][t] = 0.f;
        }
      }
    }

    float m = -INFINITY, denom = 0.f;
    float acc[2][8];
#pragma unroll
    for (int j = 0; j < 2; ++j)
#pragma unroll
      for (int t = 0; t < 8; ++t) acc[j][t] = 0.f;

#define EDGE_LOGIT(PAIR, VH0, VH1, PART)                                   \
    {                                                                      \
      const u16x8* xs = (const u16x8*)(xlr + (long)(PAIR).x * NW);         \
      float ea = __int_as_float((PAIR).y);                                 \
      VH0 = xs[q0];                                                        \
      if (ok1) VH1 = xs[q1];                                               \
      else { u16x8 zz = {0,0,0,0,0,0,0,0}; VH1 = zz; }                     \
      PART = 0.f;                                                          \
      _Pragma("unroll")                                                    \
      for (int t = 0; t < 8; ++t) {                                        \
        float tt = bf2f(VH0[t]) + xrv[0][t] + ea * wev[0][t];              \
        tt = (tt >= 0.f) ? tt : NEG_SLOPE * tt;                            \
        PART = fmaf(attv[0][t], tt, PART);                                 \
        float uu = bf2f(VH1[t]) + xrv[1][t] + ea * wev[1][t];              \
        uu = (uu >= 0.f) ? uu : NEG_SLOPE * uu;                            \
        PART = fmaf(attv[1][t], uu, PART);                                 \
      }                                                                    \
    }

#define ONLINE_UPDATE(PART, VH0, VH1)                                      \
    {                                                                      \
      if ((PART) > m) {                                                    \
        float sc = __expf(m - (PART));                                     \
        denom = denom * sc + 1.f;                                          \
        _Pragma("unroll")                                                  \
        for (int t = 0; t < 8; ++t) {                                      \
          acc[0][t] = fmaf(acc[0][t], sc, bf2f(VH0[t]));                   \
          acc[1][t] = fmaf(acc[1][t], sc, bf2f(VH1[t]));                   \
        }                                                                  \
        m = (PART);                                                        \
      } else {                                                             \
        float w = __expf((PART) - m);                                      \
        denom += w;                                                        \
        _Pragma("unroll")                                                  \
        for (int t = 0; t < 8; ++t) {                                      \
          acc[0][t] = fmaf(w, bf2f(VH0[t]), acc[0][t]);                    \
          acc[1][t] = fmaf(w, bf2f(VH1[t]), acc[1][t]);                    \
        }                                                                  \
      }                                                                    \
    }

    int i = beg;
    for (; i + 2 <= end; i += 2) {
      int2 p0 = spair[i], p1 = spair[i + 1];
      u16x8 a0, a1, b0, b1;
      float part0, part1;
      EDGE_LOGIT(p0, a0, a1, part0);
      EDGE_LOGIT(p1, b0, b1, part1);
#pragma unroll
      for (int off = 32; off > 0; off >>= 1) {
        part0 += __shfl_xor(part0, off, 64);
        part1 += __shfl_xor(part1, off, 64);
      }
      ONLINE_UPDATE(part0, a0, a1);
      ONLINE_UPDATE(part1, b0, b1);
    }
    if (i < end) {
      int2 p0 = spair[i];
      u16x8 a0, a1;
      float part0;
      EDGE_LOGIT(p0, a0, a1, part0);
#pragma unroll
      for (int off = 32; off > 0; off >>= 1) part0 += __shfl_xor(part0, off, 64);
      ONLINE_UPDATE(part0, a0, a1);
    }
#undef EDGE_LOGIT
#undef ONLINE_UPDATE

    float inv = 1.f / (denom + 1e-16f);
    if (ACT == 0) {
      us* orow = hout + ((long)d << 10);
#pragma unroll
      for (int j = 0; j < 2; ++j) {
        int qq = lane + 64 * j;
        u16x8 pk = {0, 0, 0, 0, 0, 0, 0, 0};
        if (qq < 125) {
          const float4 b0 = ((const float4*)bias)[2 * qq], b1 = ((const float4*)bias)[2 * qq + 1];
          const float bb[8] = {b0.x, b0.y, b0.z, b0.w, b1.x, b1.y, b1.z, b1.w};
#pragma unroll
          for (int t = 0; t < 8; ++t)
            pk[t] = f2bf(fmaxf(fmaf(acc[j][t], inv, bb[t]), 0.f));
        }
        ((u16x8*)orow)[qq] = pk;   // qq in [0,128): covers data + zero pad cols
      }
    } else {
#pragma unroll
      for (int j = 0; j < 2; ++j) {
        int qq = lane + 64 * j;
        if (qq < 125) {
          const float4 b0 = ((const float4*)bias)[2 * qq], b1 = ((const float4*)bias)[2 * qq + 1];
          const float bb[8] = {b0.x, b0.y, b0.z, b0.w, b1.x, b1.y, b1.z, b1.w};
          float o[8];
#pragma unroll
          for (int t = 0; t < 8; ++t)
            o[t] = 1.f / (1.f + __expf(-fmaf(acc[j][t], inv, bb[t])));
          float4* op = (float4*)(fout + (long)d * C_DIM + 8 * qq);
          op[0] = make_float4(o[0], o[1], o[2], o[3]);
          op[1] = make_float4(o[4], o[5], o[6], o[7]);
        }
      }
    }
  }
}

// ===================== launch =====================
extern "C" void kernel_launch(void* const* d_in, const int* in_sizes, int n_in,
                              void* d_out, int out_size, void* d_ws, size_t ws_size,
                              hipStream_t stream) {
  const float* x     = (const float*)d_in[0];
  const int*   ei    = (const int*)d_in[1];
  const float* eattr = (const float*)d_in[2];
  const float* w1l   = (const float*)d_in[3];
  const float* b1l   = (const float*)d_in[4];
  const float* w1r   = (const float*)d_in[5];
  const float* b1r   = (const float*)d_in[6];
  const float* w1e   = (const float*)d_in[7];
  const float* att1  = (const float*)d_in[8];
  const float* bias1 = (const float*)d_in[9];
  const float* w2l   = (const float*)d_in[10];
  const float* b2l   = (const float*)d_in[11];
  const float* w2r   = (const float*)d_in[12];
  const float* b2r   = (const float*)d_in[13];
  const float* w2e   = (const float*)d_in[14];
  const float* att2  = (const float*)d_in[15];
  const float* bias2 = (const float*)d_in[16];
  float* out = (float*)d_out;

  // ws layout (bytes), total ~130 MB (round-1 used 161MB OK):
  char* w = (char*)d_ws;
  us*  xlr  = (us*)w;                                  // 20096*2048*2 = 82,313,216
  us*  Abf  = (us*)(w + 82313216L);                    // 20096*1024*2 = 41,156,608
  us*  W2   = (us*)(w + 123469824L);                   // 2048*1024*2  =  4,194,304
  int2* spair = (int2*)(w + 127664128L);               // 256000*8     =  2,048,000
  int* row_ptr = (int*)(w + 129712128L);               // 20001*4
  int* cursor  = row_ptr + (N_NODES + 1);
  int* counts  = cursor + N_NODES;

  const int* esrc = ei;
  const int* edst = ei + N_EDGES;

  // ---- CSR by dst, with sorted (src, eattr) pairs ----
  hipMemsetAsync(counts, 0, N_NODES * sizeof(int), stream);
  count_k<<<(N_EDGES + 255) / 256, 256, 0, stream>>>(edst, counts);
  scan_k<<<1, 1024, 0, stream>>>(counts, row_ptr, cursor);
  scatter_k<<<(N_EDGES + 255) / 256, 256, 0, stream>>>(esrc, eattr, edst, cursor, spair);

  // ---- layer 1 ----
  cvt_pad_k<<<4096, 256, 0, stream>>>(x, Abf, N_NODES, F_IN, MPAD);
  cvt_pad_k<<<1024, 256, 0, stream>>>(w1l, W2, C_DIM, F_IN, 1024);
  cvt_pad_k<<<1024, 256, 0, stream>>>(w1r, W2 + 1024 * 1024, C_DIM, F_IN, 1024);
  gemm_mfma_k<<<2512, 256, 0, stream>>>(Abf, W2, b1l, b1r, xlr);
  edge_agg_k<0><<<2048, 256, 0, stream>>>(xlr, spair, row_ptr, w1e, att1, bias1, Abf, nullptr);

  // ---- layer 2 (h is bf16 in Abf; pad rows 20000..20095 still zero from cvt) ----
  cvt_pad_k<<<1024, 256, 0, stream>>>(w2l, W2, C_DIM, C_DIM, 1024);
  cvt_pad_k<<<1024, 256, 0, stream>>>(w2r, W2 + 1024 * 1024, C_DIM, C_DIM, 1024);
  gemm_mfma_k<<<2512, 256, 0, stream>>>(Abf, W2, b2l, b2r, xlr);
  edge_agg_k<1><<<2048, 256, 0, stream>>>(xlr, spair, row_ptr, w2e, att2, bias2, nullptr, out);
}